// Round 3
// baseline (534.251 us; speedup 1.0000x reference)
//
#include <hip/hip_runtime.h>
#include <hip/hip_bf16.h>
#include <math.h>

// Problem constants: B=4, C=D=256, H=W=128, HID=1024, N = B*H*W = 65536.
#define NPIX  65536
#define CCH   256
#define HWSZ  16384
#define WIDTH 128
#define HID   1024

typedef unsigned short u16;
typedef __bf16 bf16x8 __attribute__((ext_vector_type(8)));
typedef float  floatx4 __attribute__((ext_vector_type(4)));

__device__ __forceinline__ float bf2f(u16 u) {
  union { unsigned int i; float f; } c; c.i = ((unsigned int)u) << 16; return c.f;
}
__device__ __forceinline__ float bflo(unsigned int u) {
  union { unsigned int i; float f; } c; c.i = u << 16; return c.f;
}
__device__ __forceinline__ float bfhi(unsigned int u) {
  union { unsigned int i; float f; } c; c.i = u & 0xffff0000u; return c.f;
}
__device__ __forceinline__ u16 f2bf(float f) {
  union { float f; unsigned int i; } c; c.f = f;
  unsigned int x = c.i;
  x += 0x7fffu + ((x >> 16) & 1u);   // round-to-nearest-even
  return (u16)(x >> 16);
}

// async global->LDS, 16B per lane; LDS dest is wave-uniform base + lane*16.
__device__ __forceinline__ void async16(const void* g, void* l) {
  __builtin_amdgcn_global_load_lds(
      (const __attribute__((address_space(1))) void*)g,
      (__attribute__((address_space(3))) void*)l, 16, 0, 0);
}

// ---------------------------------------------------------------------------
// Weight transpose + fp32->bf16: dst[c*R + r] = bf16(src[r*C + c])
__global__ __launch_bounds__(256) void wtrans_kernel(
    const float* __restrict__ src, u16* __restrict__ dst, int R, int C) {
  __shared__ float tile[32][33];
  const int tx = threadIdx.x & 31, ty = threadIdx.x >> 5;  // 32 x 8
  const int r0 = blockIdx.y * 32, c0 = blockIdx.x * 32;
#pragma unroll
  for (int i = 0; i < 32; i += 8)
    tile[ty + i][tx] = src[(size_t)(r0 + ty + i) * C + c0 + tx];
  __syncthreads();
#pragma unroll
  for (int i = 0; i < 32; i += 8)
    dst[(size_t)(c0 + ty + i) * R + r0 + tx] = f2bf(tile[tx][ty + i]);
}

__global__ __launch_bounds__(256) void concat_bias_kernel(
    const float* __restrict__ bq, const float* __restrict__ bk,
    const float* __restrict__ bv, float* __restrict__ dst) {
  const int i = blockIdx.x * 256 + threadIdx.x;   // grid 3
  if (i < 256) dst[i] = bq[i];
  else if (i < 512) dst[i] = bk[i - 256];
  else if (i < 768) dst[i] = bv[i - 512];
}

// ---------------------------------------------------------------------------
// LayerNorm1: x [B,C,H,W] fp32 -> n1 [N,256] bf16
__global__ __launch_bounds__(256) void ln1_kernel(
    const float* __restrict__ x, const float* __restrict__ g,
    const float* __restrict__ bb, u16* __restrict__ n1) {
  __shared__ float sx[32][257];
  __shared__ float sred[16][32];
  __shared__ float sm[32], sr[32];
  const int tx = threadIdx.x;
  const int p0 = blockIdx.x * 32;
  {
    const int pix = tx & 31, cpart = tx >> 5;
    const int p = p0 + pix;
    const int b = p >> 14, hw = p & (HWSZ - 1);
    const float* xb = x + ((size_t)b * CCH) * HWSZ + hw;
    float s = 0.f, s2 = 0.f;
#pragma unroll 4
    for (int i = 0; i < 32; i++) {
      const int c = cpart * 32 + i;
      const float v = xb[(size_t)c * HWSZ];
      sx[pix][c] = v;
      s += v; s2 += v * v;
    }
    sred[cpart][pix] = s; sred[8 + cpart][pix] = s2;
  }
  __syncthreads();
  if (tx < 32) {
    float s = 0.f, s2 = 0.f;
#pragma unroll
    for (int j = 0; j < 8; j++) { s += sred[j][tx]; s2 += sred[8 + j][tx]; }
    const float m = s * (1.0f / 256.0f);
    const float var = s2 * (1.0f / 256.0f) - m * m;
    sm[tx] = m; sr[tx] = rsqrtf(var + 1e-5f);
  }
  __syncthreads();
  const float gc = g[tx], bc = bb[tx];
#pragma unroll 4
  for (int i = 0; i < 32; i++) {
    const float v = (sx[i][tx] - sm[i]) * sr[i] * gc + bc;
    n1[(size_t)(p0 + i) * CCH + tx] = f2bf(v);
  }
}

// ---------------------------------------------------------------------------
// Residual + LayerNorm2: x1 = x + attn (fp32 out), n2 = LN(x1) bf16
__global__ __launch_bounds__(256) void res_ln2_kernel(
    const float* __restrict__ x, const u16* __restrict__ attn,
    const float* __restrict__ g, const float* __restrict__ bb,
    float* __restrict__ x1, u16* __restrict__ n2) {
  __shared__ float sx[32][257];
  __shared__ float sred[16][32];
  __shared__ float sm[32], sr[32];
  const int tx = threadIdx.x;
  const int p0 = blockIdx.x * 32;
  {
    const int pix = tx & 31, cpart = tx >> 5;
    const int p = p0 + pix;
    const int b = p >> 14, hw = p & (HWSZ - 1);
    const float* xb = x + ((size_t)b * CCH) * HWSZ + hw;
#pragma unroll 4
    for (int i = 0; i < 32; i++) {
      const int c = cpart * 32 + i;
      sx[pix][c] = xb[(size_t)c * HWSZ];
    }
  }
  __syncthreads();
#pragma unroll 4
  for (int i = 0; i < 32; i++) {
    const float v = sx[i][tx] + bf2f(attn[(size_t)(p0 + i) * CCH + tx]);
    sx[i][tx] = v;
    x1[(size_t)(p0 + i) * CCH + tx] = v;
  }
  __syncthreads();
  {
    const int pix = tx & 31, cpart = tx >> 5;
    float s = 0.f, s2 = 0.f;
#pragma unroll 4
    for (int i = 0; i < 32; i++) {
      const float v = sx[pix][cpart * 32 + i];
      s += v; s2 += v * v;
    }
    sred[cpart][pix] = s; sred[8 + cpart][pix] = s2;
  }
  __syncthreads();
  if (tx < 32) {
    float s = 0.f, s2 = 0.f;
#pragma unroll
    for (int j = 0; j < 8; j++) { s += sred[j][tx]; s2 += sred[8 + j][tx]; }
    const float m = s * (1.0f / 256.0f);
    const float var = s2 * (1.0f / 256.0f) - m * m;
    sm[tx] = m; sr[tx] = rsqrtf(var + 1e-5f);
  }
  __syncthreads();
  const float gc = g[tx], bc = bb[tx];
#pragma unroll 4
  for (int i = 0; i < 32; i++) {
    const float v = (sx[i][tx] - sm[i]) * sr[i] * gc + bc;
    n2[(size_t)(p0 + i) * CCH + tx] = f2bf(v);
  }
}

// ---------------------------------------------------------------------------
// 3x3 neighborhood attention over fused qkv [N,768] (q|k|v per row).
__global__ __launch_bounds__(256) void attn_kernel(
    const u16* __restrict__ qkv, u16* __restrict__ attn) {
  const int tid = threadIdx.x;
  const int wave = tid >> 6, lane = tid & 63;
  const int p = blockIdx.x * 4 + wave;
  const int hw = p & (HWSZ - 1);
  const int hh = hw >> 7, ww = hw & (WIDTH - 1);
  const u16* rowp = qkv + (size_t)p * 768 + lane * 4;
  const uint2 qr = *(const uint2*)rowp;
  const float qf0 = bflo(qr.x), qf1 = bfhi(qr.x);
  const float qf2 = bflo(qr.y), qf3 = bfhi(qr.y);
  float sc[9];
#pragma unroll
  for (int n = 0; n < 9; n++) {
    const int dy = n / 3 - 1, dx = n % 3 - 1;
    const int y = hh + dy, x2 = ww + dx;
    float s = -1e30f;
    if (y >= 0 && y < 128 && x2 >= 0 && x2 < 128) {   // wave-uniform branch
      const uint2 kr = *(const uint2*)(rowp + 256 + (dy * WIDTH + dx) * 768);
      float d = qf0 * bflo(kr.x) + qf1 * bfhi(kr.x)
              + qf2 * bflo(kr.y) + qf3 * bfhi(kr.y);
#pragma unroll
      for (int o = 32; o >= 1; o >>= 1) d += __shfl_xor(d, o, 64);
      s = d * 0.0625f;   // 1/sqrt(256)
    }
    sc[n] = s;
  }
  float mx = sc[0];
#pragma unroll
  for (int n = 1; n < 9; n++) mx = fmaxf(mx, sc[n]);
  float wgt[9], wsum = 0.f;
#pragma unroll
  for (int n = 0; n < 9; n++) { wgt[n] = __expf(sc[n] - mx); wsum += wgt[n]; }
  const float inv = 1.0f / wsum;
  float a0 = 0.f, a1 = 0.f, a2 = 0.f, a3 = 0.f;
#pragma unroll
  for (int n = 0; n < 9; n++) {
    const int dy = n / 3 - 1, dx = n % 3 - 1;
    const int y = hh + dy, x2 = ww + dx;
    if (y >= 0 && y < 128 && x2 >= 0 && x2 < 128) {
      const uint2 vr = *(const uint2*)(rowp + 512 + (dy * WIDTH + dx) * 768);
      const float wn = wgt[n] * inv;
      a0 += wn * bflo(vr.x); a1 += wn * bfhi(vr.x);
      a2 += wn * bflo(vr.y); a3 += wn * bfhi(vr.y);
    }
  }
  uint2 o;
  o.x = ((unsigned int)f2bf(a1) << 16) | (unsigned int)f2bf(a0);
  o.y = ((unsigned int)f2bf(a3) << 16) | (unsigned int)f2bf(a2);
  *(uint2*)(attn + (size_t)p * CCH + lane * 4) = o;
}

// ---------------------------------------------------------------------------
// Register-A GEMM v2: 64-row tiles (grid = M/64), 4 waves as 2x2 over
// (32 rows x 32 cols). A fragments in VGPRs, read from global exactly once.
// B (weights) staged to LDS in col-minor slot layout:
//   slot(c,u) = (c>>3)*(8*K16) + u*8 + (c&7)    [one slot = 16 B]
// -> async16 writes are lane-contiguous (slot = round*256 + tid), and frag
//    reads have every aligned 8-lane run covering all 32 banks exactly once
//    (conflict-free; R1's layout was 8-way conflicted -> 6.3M SQ_LDS_BANK_CONFLICT).
// EPI 0: bf16(acc+bias) -> outb [M,768]
// EPI 1: bf16(gelu_tanh(acc+bias)) -> outb [M,1024]
// EPI 2: acc+bias+x1 -> fp32 transposed [B,C,H,W], float4 stores
template <int NCH, int KCH, int KT, int EPI>
__global__ __launch_bounds__(256, 4) void gemm_regA(
    const u16* __restrict__ A, const u16* __restrict__ BT,
    const float* __restrict__ bias, const float* __restrict__ x1,
    u16* __restrict__ outb, float* __restrict__ outf, int Kglb) {
  constexpr int KS    = KT / 32;        // MFMA k-steps per chunk
  constexpr int K16   = KT / 8;         // 16B units per col
  constexpr int SLOT  = 64 * K16;       // 16B slots per 64-col chunk
  constexpr int CALLS = SLOT / 256;     // async rounds (256 thr x 16B each)
  constexpr int COLPC = 256 / K16;      // cols advanced per round
  constexpr int NACC  = (KCH > 1) ? NCH : 1;
  __shared__ u16 sB[SLOT * 8];

  const int tid  = threadIdx.x;
  const int wave = tid >> 6, lane = tid & 63;
  const int quad = lane >> 4, l16 = lane & 15;
  const int m0  = blockIdx.x * 64;
  const int wr  = (wave & 1) * 32;
  const int wcq = (wave >> 1) * 32;

  // stage-side per-thread constants: slot s = round*256 + tid
  //   col_in_chunk = (s / (8*K16))*8 + (s&7),  u = (s % (8*K16)) >> 3
  const int stCol = (tid & 7) + ((K16 == 16) ? ((tid >> 7) << 3) : 0);
  const int stU   = (K16 == 16) ? ((tid & 127) >> 3) : (tid >> 3);
  const u16* stBase = BT + (size_t)stCol * Kglb + stU * 8;
  u16* stLds = sB + wave * 512;         // + round*2048 (u16 units)

  // read-side LDS bases (u16 idx) for this lane's two 16-col groups
  int sbN[2];
#pragma unroll
  for (int ni = 0; ni < 2; ni++) {
    const int c = wcq + ni * 16 + l16;
    sbN[ni] = ((c >> 3) * (8 * K16) + (c & 7)) * 8 + quad * 64;
  }

  const u16* aRow = A + (size_t)(m0 + wr + l16) * Kglb + quad * 8;

  bf16x8 afr[2][KS];
  floatx4 acc[NACC][2][2];

  auto stage = [&](int idx) {
    const int kc = idx / NCH, ch = idx % NCH;
    const u16* g = stBase + (size_t)(ch * 64) * Kglb + kc * KT;
#pragma unroll
    for (int i = 0; i < CALLS; i++)
      async16(g + (size_t)(i * COLPC) * Kglb, stLds + i * 2048);
  };
  auto loadA = [&](int kc) {
#pragma unroll
    for (int mi = 0; mi < 2; mi++)
#pragma unroll
      for (int ks = 0; ks < KS; ks++)
        afr[mi][ks] = *(const bf16x8*)(aRow + (size_t)mi * 16 * Kglb + kc * KT + ks * 32);
  };
  auto computeC = [&](int ci) {
#pragma unroll
    for (int ks = 0; ks < KS; ks++) {
      const bf16x8 b0 = *(const bf16x8*)&sB[sbN[0] + ks * 256];
      const bf16x8 b1 = *(const bf16x8*)&sB[sbN[1] + ks * 256];
#pragma unroll
      for (int mi = 0; mi < 2; mi++) {
        acc[ci][mi][0] = __builtin_amdgcn_mfma_f32_16x16x32_bf16(
            afr[mi][ks], b0, acc[ci][mi][0], 0, 0, 0);
        acc[ci][mi][1] = __builtin_amdgcn_mfma_f32_16x16x32_bf16(
            afr[mi][ks], b1, acc[ci][mi][1], 0, 0, 0);
      }
    }
  };
  auto epilogue = [&](int ci, int ch) {
#pragma unroll
    for (int mi = 0; mi < 2; mi++)
#pragma unroll
      for (int ni = 0; ni < 2; ni++) {
        const int col = ch * 64 + wcq + ni * 16 + l16;
        const float bs = bias[col];
        const int row0 = m0 + wr + mi * 16 + quad * 4;
        if constexpr (EPI == 2) {
          floatx4 vv;
#pragma unroll
          for (int r = 0; r < 4; r++)
            vv[r] = acc[ci][mi][ni][r] + bs + x1[(size_t)(row0 + r) * CCH + col];
          *(floatx4*)&outf[((size_t)((row0 >> 14) * CCH + col)) * HWSZ + (row0 & (HWSZ - 1))] = vv;
        } else {
#pragma unroll
          for (int r = 0; r < 4; r++) {
            float val = acc[ci][mi][ni][r] + bs;
            if constexpr (EPI == 0) {
              outb[(size_t)(row0 + r) * 768 + col] = f2bf(val);
            } else {
              const float t = 0.7978845608028654f * (val + 0.044715f * val * val * val);
              const float e = __expf(2.0f * t);
              const float th = 1.0f - 2.0f / (e + 1.0f);   // tanh, inf-safe
              val = 0.5f * val * (1.0f + th);
              outb[(size_t)(row0 + r) * HID + col] = f2bf(val);
            }
          }
        }
      }
  };

  if constexpr (KCH == 1) {
    stage(0);
    loadA(0);
#pragma unroll 1
    for (int ch = 0; ch < NCH; ++ch) {
      __syncthreads();                      // staging of chunk ch complete
#pragma unroll
      for (int mi = 0; mi < 2; mi++)
#pragma unroll
        for (int ni = 0; ni < 2; ni++)
          acc[0][mi][ni] = (floatx4){0.f, 0.f, 0.f, 0.f};
      computeC(0);
      __syncthreads();                      // all waves done reading sB
      if (ch + 1 < NCH) stage(ch + 1);      // async prefetch next chunk
      epilogue(0, ch);
    }
  } else {
    stage(0);
#pragma unroll
    for (int ci = 0; ci < NACC; ci++)
#pragma unroll
      for (int mi = 0; mi < 2; mi++)
#pragma unroll
        for (int ni = 0; ni < 2; ni++)
          acc[ci][mi][ni] = (floatx4){0.f, 0.f, 0.f, 0.f};
#pragma unroll 1
    for (int kc = 0; kc < KCH; ++kc) {
      loadA(kc);
#pragma unroll
      for (int ch = 0; ch < NCH; ++ch) {
        __syncthreads();
        computeC(ch);
        __syncthreads();
        const int nxt = kc * NCH + ch + 1;
        if (nxt < KCH * NCH) stage(nxt);
      }
    }
#pragma unroll
    for (int ch = 0; ch < NCH; ++ch) epilogue(ch, ch);
  }
}

// ---------------------------------------------------------------------------
extern "C" void kernel_launch(void* const* d_in, const int* in_sizes, int n_in,
                              void* d_out, int out_size, void* d_ws, size_t ws_size,
                              hipStream_t stream) {
  const float* x    = (const float*)d_in[0];
  const float* wq   = (const float*)d_in[1];
  const float* bq   = (const float*)d_in[2];
  const float* wk   = (const float*)d_in[3];
  const float* bk   = (const float*)d_in[4];
  const float* wv   = (const float*)d_in[5];
  const float* bv   = (const float*)d_in[6];
  const float* ln1g = (const float*)d_in[7];
  const float* ln1b = (const float*)d_in[8];
  const float* ln2g = (const float*)d_in[9];
  const float* ln2b = (const float*)d_in[10];
  const float* fc1w = (const float*)d_in[11];
  const float* fc1b = (const float*)d_in[12];
  const float* fc2w = (const float*)d_in[13];
  const float* fc2b = (const float*)d_in[14];
  float* out = (float*)d_out;

  // Workspace (aliased by liveness), total ~225.4 MB:
  //   [0,64)    x1 fp32                (res_ln2 -> fc2)
  //   [64,192)  h bf16 [N,1024]        (fc1 -> fc2); overlays:
  //     [64,160)  qkv bf16 [N,768]     (qkv-gemm -> attn)
  //     [160,192) n1 / attn bf16       (ln1 -> qkv-gemm; attn -> res_ln2)
  //   [192,224) n2 bf16                (res_ln2 -> fc1)
  //   [224,..)  bf16 weights + fused bias
  char* ws = (char*)d_ws;
  const size_t MB = (size_t)1 << 20;
  float* x1   = (float*)(ws);
  u16* qkv    = (u16*)(ws + 64 * MB);
  u16* hbuf   = (u16*)(ws + 64 * MB);
  u16* n1     = (u16*)(ws + 160 * MB);
  u16* attnb  = n1;
  u16* n2     = (u16*)(ws + 192 * MB);
  u16* wqkvT  = (u16*)(ws + 224 * MB);      // [768,256]
  u16* f1T    = wqkvT + 768 * 256;          // [1024,256]
  u16* f2T    = f1T + 1024 * 256;           // [256,1024]
  float* bqkv = (float*)(f2T + 256 * 1024); // [768]

  dim3 blk(256);
  wtrans_kernel<<<dim3(8, 8), blk, 0, stream>>>(wq, wqkvT, 256, 256);
  wtrans_kernel<<<dim3(8, 8), blk, 0, stream>>>(wk, wqkvT + 256 * 256, 256, 256);
  wtrans_kernel<<<dim3(8, 8), blk, 0, stream>>>(wv, wqkvT + 512 * 256, 256, 256);
  wtrans_kernel<<<dim3(32, 8), blk, 0, stream>>>(fc1w, f1T, 256, 1024);
  wtrans_kernel<<<dim3(8, 32), blk, 0, stream>>>(fc2w, f2T, 1024, 256);
  concat_bias_kernel<<<dim3(3), blk, 0, stream>>>(bq, bk, bv, bqkv);

  ln1_kernel<<<NPIX / 32, blk, 0, stream>>>(x, ln1g, ln1b, n1);

  // fused QKV: [N,256] x [768,256]^T -> qkv [N,768]
  gemm_regA<12, 1, 256, 0><<<dim3(NPIX / 64), blk, 0, stream>>>(
      n1, wqkvT, bqkv, nullptr, qkv, nullptr, 256);

  attn_kernel<<<NPIX / 4, blk, 0, stream>>>(qkv, attnb);

  res_ln2_kernel<<<NPIX / 32, blk, 0, stream>>>(x, attnb, ln2g, ln2b, x1, n2);

  // fc1 + gelu: [N,256] x [1024,256]^T -> h [N,1024]
  gemm_regA<16, 1, 256, 1><<<dim3(NPIX / 64), blk, 0, stream>>>(
      n2, f1T, fc1b, nullptr, hbuf, nullptr, 256);

  // fc2 + residual + transpose: [N,1024] x [256,1024]^T -> out [B,C,H,W]
  gemm_regA<4, 8, 128, 2><<<dim3(NPIX / 64), blk, 0, stream>>>(
      hbuf, f2T, fc2b, x1, nullptr, out, 1024);
}

// Round 5
// 514.372 us; speedup vs baseline: 1.0386x; 1.0386x over previous
//
#include <hip/hip_runtime.h>
#include <hip/hip_bf16.h>
#include <math.h>

// Problem constants: B=4, C=D=256, H=W=128, HID=1024, N = B*H*W = 65536.
#define NPIX  65536
#define CCH   256
#define HWSZ  16384
#define WIDTH 128
#define HID   1024

typedef unsigned short u16;
typedef __bf16 bf16x8 __attribute__((ext_vector_type(8)));
typedef float  floatx4 __attribute__((ext_vector_type(4)));

__device__ __forceinline__ float bf2f(u16 u) {
  union { unsigned int i; float f; } c; c.i = ((unsigned int)u) << 16; return c.f;
}
__device__ __forceinline__ float bflo(unsigned int u) {
  union { unsigned int i; float f; } c; c.i = u << 16; return c.f;
}
__device__ __forceinline__ float bfhi(unsigned int u) {
  union { unsigned int i; float f; } c; c.i = u & 0xffff0000u; return c.f;
}
__device__ __forceinline__ u16 f2bf(float f) {
  union { float f; unsigned int i; } c; c.f = f;
  unsigned int x = c.i;
  x += 0x7fffu + ((x >> 16) & 1u);   // round-to-nearest-even
  return (u16)(x >> 16);
}

// ---------------------------------------------------------------------------
// Weight fp32 [K,N] -> fragment-major bf16 blob:
// unit u = g*(K/32) + kb   (g = 16-col group, kb = 32-k block); unit = 512 u16.
// dst[u*512 + lane*8 + e] = bf16(src[(kb*32 + (lane>>4)*8 + e)*N + g*16 + (lane&15)])
// A wave's MFMA B-fragment load is then one coalesced 1KB global_load_dwordx4.
// grid = (#groups * K/32) / 4  (4 units per 256-thread block)
__global__ __launch_bounds__(256) void wfrag_kernel(
    const float* __restrict__ src, u16* __restrict__ dst, int N, int K) {
  const int tid = threadIdx.x;
  const int u = blockIdx.x * 4 + (tid >> 6);
  const int lane = tid & 63, quad = lane >> 4, l16 = lane & 15;
  const int K32 = K >> 5;
  const int g = u / K32, kb = u - g * K32;
  const int n = g * 16 + l16;
  const int k0 = kb * 32 + quad * 8;
  u16 tmp[8];
#pragma unroll
  for (int e = 0; e < 8; e++) tmp[e] = f2bf(src[(size_t)(k0 + e) * N + n]);
  *(bf16x8*)(dst + ((size_t)u * 64 + lane) * 8) = *(bf16x8*)tmp;
}

__global__ __launch_bounds__(256) void concat_bias_kernel(
    const float* __restrict__ bq, const float* __restrict__ bk,
    const float* __restrict__ bv, float* __restrict__ dst) {
  const int i = blockIdx.x * 256 + threadIdx.x;   // grid 3
  if (i < 256) dst[i] = bq[i];
  else if (i < 512) dst[i] = bk[i - 256];
  else if (i < 768) dst[i] = bv[i - 512];
}

// ---------------------------------------------------------------------------
// LayerNorm1: x [B,C,H,W] fp32 -> n1 [N,256] bf16
__global__ __launch_bounds__(256) void ln1_kernel(
    const float* __restrict__ x, const float* __restrict__ g,
    const float* __restrict__ bb, u16* __restrict__ n1) {
  __shared__ float sx[32][257];
  __shared__ float sred[16][32];
  __shared__ float sm[32], sr[32];
  const int tx = threadIdx.x;
  const int p0 = blockIdx.x * 32;
  {
    const int pix = tx & 31, cpart = tx >> 5;
    const int p = p0 + pix;
    const int b = p >> 14, hw = p & (HWSZ - 1);
    const float* xb = x + ((size_t)b * CCH) * HWSZ + hw;
    float s = 0.f, s2 = 0.f;
#pragma unroll 4
    for (int i = 0; i < 32; i++) {
      const int c = cpart * 32 + i;
      const float v = xb[(size_t)c * HWSZ];
      sx[pix][c] = v;
      s += v; s2 += v * v;
    }
    sred[cpart][pix] = s; sred[8 + cpart][pix] = s2;
  }
  __syncthreads();
  if (tx < 32) {
    float s = 0.f, s2 = 0.f;
#pragma unroll
    for (int j = 0; j < 8; j++) { s += sred[j][tx]; s2 += sred[8 + j][tx]; }
    const float m = s * (1.0f / 256.0f);
    const float var = s2 * (1.0f / 256.0f) - m * m;
    sm[tx] = m; sr[tx] = rsqrtf(var + 1e-5f);
  }
  __syncthreads();
  const float gc = g[tx], bc = bb[tx];
#pragma unroll 4
  for (int i = 0; i < 32; i++) {
    const float v = (sx[i][tx] - sm[i]) * sr[i] * gc + bc;
    n1[(size_t)(p0 + i) * CCH + tx] = f2bf(v);
  }
}

// ---------------------------------------------------------------------------
// Residual + LayerNorm2: x1 = x + attn (fp32 out), n2 = LN(x1) bf16
__global__ __launch_bounds__(256) void res_ln2_kernel(
    const float* __restrict__ x, const u16* __restrict__ attn,
    const float* __restrict__ g, const float* __restrict__ bb,
    float* __restrict__ x1, u16* __restrict__ n2) {
  __shared__ float sx[32][257];
  __shared__ float sred[16][32];
  __shared__ float sm[32], sr[32];
  const int tx = threadIdx.x;
  const int p0 = blockIdx.x * 32;
  {
    const int pix = tx & 31, cpart = tx >> 5;
    const int p = p0 + pix;
    const int b = p >> 14, hw = p & (HWSZ - 1);
    const float* xb = x + ((size_t)b * CCH) * HWSZ + hw;
#pragma unroll 4
    for (int i = 0; i < 32; i++) {
      const int c = cpart * 32 + i;
      sx[pix][c] = xb[(size_t)c * HWSZ];
    }
  }
  __syncthreads();
#pragma unroll 4
  for (int i = 0; i < 32; i++) {
    const float v = sx[i][tx] + bf2f(attn[(size_t)(p0 + i) * CCH + tx]);
    sx[i][tx] = v;
    x1[(size_t)(p0 + i) * CCH + tx] = v;
  }
  __syncthreads();
  {
    const int pix = tx & 31, cpart = tx >> 5;
    float s = 0.f, s2 = 0.f;
#pragma unroll 4
    for (int i = 0; i < 32; i++) {
      const float v = sx[pix][cpart * 32 + i];
      s += v; s2 += v * v;
    }
    sred[cpart][pix] = s; sred[8 + cpart][pix] = s2;
  }
  __syncthreads();
  if (tx < 32) {
    float s = 0.f, s2 = 0.f;
#pragma unroll
    for (int j = 0; j < 8; j++) { s += sred[j][tx]; s2 += sred[8 + j][tx]; }
    const float m = s * (1.0f / 256.0f);
    const float var = s2 * (1.0f / 256.0f) - m * m;
    sm[tx] = m; sr[tx] = rsqrtf(var + 1e-5f);
  }
  __syncthreads();
  const float gc = g[tx], bc = bb[tx];
#pragma unroll 4
  for (int i = 0; i < 32; i++) {
    const float v = (sx[i][tx] - sm[i]) * sr[i] * gc + bc;
    n2[(size_t)(p0 + i) * CCH + tx] = f2bf(v);
  }
}

// ---------------------------------------------------------------------------
// 3x3 neighborhood attention over fused qkv [N,768] (q|k|v per row).
__global__ __launch_bounds__(256) void attn_kernel(
    const u16* __restrict__ qkv, u16* __restrict__ attn) {
  const int tid = threadIdx.x;
  const int wave = tid >> 6, lane = tid & 63;
  const int p = blockIdx.x * 4 + wave;
  const int hw = p & (HWSZ - 1);
  const int hh = hw >> 7, ww = hw & (WIDTH - 1);
  const u16* rowp = qkv + (size_t)p * 768 + lane * 4;
  const uint2 qr = *(const uint2*)rowp;
  const float qf0 = bflo(qr.x), qf1 = bfhi(qr.x);
  const float qf2 = bflo(qr.y), qf3 = bfhi(qr.y);
  float sc[9];
#pragma unroll
  for (int n = 0; n < 9; n++) {
    const int dy = n / 3 - 1, dx = n % 3 - 1;
    const int y = hh + dy, x2 = ww + dx;
    float s = -1e30f;
    if (y >= 0 && y < 128 && x2 >= 0 && x2 < 128) {   // wave-uniform branch
      const uint2 kr = *(const uint2*)(rowp + 256 + (dy * WIDTH + dx) * 768);
      float d = qf0 * bflo(kr.x) + qf1 * bfhi(kr.x)
              + qf2 * bflo(kr.y) + qf3 * bfhi(kr.y);
#pragma unroll
      for (int o = 32; o >= 1; o >>= 1) d += __shfl_xor(d, o, 64);
      s = d * 0.0625f;   // 1/sqrt(256)
    }
    sc[n] = s;
  }
  float mx = sc[0];
#pragma unroll
  for (int n = 1; n < 9; n++) mx = fmaxf(mx, sc[n]);
  float wgt[9], wsum = 0.f;
#pragma unroll
  for (int n = 0; n < 9; n++) { wgt[n] = __expf(sc[n] - mx); wsum += wgt[n]; }
  const float inv = 1.0f / wsum;
  float a0 = 0.f, a1 = 0.f, a2 = 0.f, a3 = 0.f;
#pragma unroll
  for (int n = 0; n < 9; n++) {
    const int dy = n / 3 - 1, dx = n % 3 - 1;
    const int y = hh + dy, x2 = ww + dx;
    if (y >= 0 && y < 128 && x2 >= 0 && x2 < 128) {
      const uint2 vr = *(const uint2*)(rowp + 512 + (dy * WIDTH + dx) * 768);
      const float wn = wgt[n] * inv;
      a0 += wn * bflo(vr.x); a1 += wn * bfhi(vr.x);
      a2 += wn * bflo(vr.y); a3 += wn * bfhi(vr.y);
    }
  }
  uint2 o;
  o.x = ((unsigned int)f2bf(a1) << 16) | (unsigned int)f2bf(a0);
  o.y = ((unsigned int)f2bf(a3) << 16) | (unsigned int)f2bf(a2);
  *(uint2*)(attn + (size_t)p * CCH + lane * 4) = o;
}

// ---------------------------------------------------------------------------
// Barrier-free register GEMM. 64-row tiles, 4 waves as 2x2 over 32rows x 32cols.
// A [M,K] bf16 row-major: fragments loaded straight from global (HBM, once).
// B: fragment-major blob (wfrag_kernel layout) -> each B-fragment is ONE
// coalesced 1KB global_load_dwordx4 per wave, L2-resident across 1024 blocks.
// No LDS, no __syncthreads: waves fully independent; latency hidden by
// compiler-scheduled ILP + 3-4 blocks/CU of TLP.   [fixes R2's barrier-drain]
// EPI 0: bf16(acc+bias) -> outb [M,768]
// EPI 1: bf16(gelu_tanh(acc+bias)) -> outb [M,1024]
// EPI 2: acc+bias+x1 -> fp32 transposed [B,C,H,W], float4 stores
template <int NCH, int KCH, int KT, int EPI>
__global__ __launch_bounds__(256, (KCH == 1) ? 4 : 3) void gemm_regB(
    const u16* __restrict__ A, const u16* __restrict__ wf,
    const float* __restrict__ bias, const float* __restrict__ x1,
    u16* __restrict__ outb, float* __restrict__ outf) {
  constexpr int K   = KCH * KT;
  constexpr int KS  = KT / 32;       // 32-k blocks per chunk
  constexpr int K32 = K / 32;        // 32-k blocks total

  const int tid  = threadIdx.x;
  const int wave = tid >> 6, lane = tid & 63;
  const int quad = lane >> 4, l16 = lane & 15;
  const int m0  = blockIdx.x * 64;
  const int wr  = (wave & 1) * 32;
  const int wcq = (wave >> 1) * 32;
  const int w2  = (wave >> 1) * 2;   // base 16-col group within a 64-col chunk

  const u16* aRow = A + (size_t)(m0 + wr + l16) * K + quad * 8;

  // B-fragment: group gidx = ch*4 + w2 + ni, 32-k block kb
  auto loadB = [&](int ch, int ni, int kb) -> bf16x8 {
    return *(const bf16x8*)(wf + (((size_t)(ch * 4 + w2 + ni) * K32 + kb) << 9)
                               + (lane << 3));
  };

  auto epilogue = [&](floatx4 (&acc)[2][2], int ch) {
#pragma unroll
    for (int mi = 0; mi < 2; mi++)
#pragma unroll
      for (int ni = 0; ni < 2; ni++) {
        const int col = ch * 64 + wcq + ni * 16 + l16;
        const float bs = bias[col];
        const int row0 = m0 + wr + mi * 16 + quad * 4;
        if constexpr (EPI == 2) {
          floatx4 vv;
#pragma unroll
          for (int r = 0; r < 4; r++)
            vv[r] = acc[mi][ni][r] + bs + x1[(size_t)(row0 + r) * CCH + col];
          *(floatx4*)&outf[((size_t)((row0 >> 14) * CCH + col)) * HWSZ + (row0 & (HWSZ - 1))] = vv;
        } else {
#pragma unroll
          for (int r = 0; r < 4; r++) {
            float val = acc[mi][ni][r] + bs;
            if constexpr (EPI == 0) {
              outb[(size_t)(row0 + r) * 768 + col] = f2bf(val);
            } else {
              const float t = 0.7978845608028654f * (val + 0.044715f * val * val * val);
              const float e = __expf(2.0f * t);
              const float th = 1.0f - 2.0f / (e + 1.0f);   // tanh, inf-safe
              val = 0.5f * val * (1.0f + th);
              outb[(size_t)(row0 + r) * HID + col] = f2bf(val);
            }
          }
        }
      }
  };

  if constexpr (KCH == 1) {
    // qkv / fc1: whole K (=256) of A in registers, loop over N-chunks.
    bf16x8 afr[2][KS];
#pragma unroll
    for (int mi = 0; mi < 2; mi++)
#pragma unroll
      for (int ks = 0; ks < KS; ks++)
        afr[mi][ks] = *(const bf16x8*)(aRow + (size_t)mi * 16 * K + ks * 32);

#pragma unroll 1
    for (int ch = 0; ch < NCH; ++ch) {
      floatx4 acc[2][2];
#pragma unroll
      for (int mi = 0; mi < 2; mi++)
#pragma unroll
        for (int ni = 0; ni < 2; ni++) acc[mi][ni] = (floatx4){0.f, 0.f, 0.f, 0.f};
#pragma unroll
      for (int ks = 0; ks < KS; ks++) {
        const bf16x8 b0 = loadB(ch, 0, ks);
        const bf16x8 b1 = loadB(ch, 1, ks);
#pragma unroll
        for (int mi = 0; mi < 2; mi++) {
          acc[mi][0] = __builtin_amdgcn_mfma_f32_16x16x32_bf16(afr[mi][ks], b0, acc[mi][0], 0, 0, 0);
          acc[mi][1] = __builtin_amdgcn_mfma_f32_16x16x32_bf16(afr[mi][ks], b1, acc[mi][1], 0, 0, 0);
        }
      }
      epilogue(acc, ch);
    }
  } else {
    // fc2: acc for all N-chunks, stream K in KT-chunks, A double-buffered.
    floatx4 acc[NCH][2][2];
#pragma unroll
    for (int ci = 0; ci < NCH; ci++)
#pragma unroll
      for (int mi = 0; mi < 2; mi++)
#pragma unroll
        for (int ni = 0; ni < 2; ni++) acc[ci][mi][ni] = (floatx4){0.f, 0.f, 0.f, 0.f};

    bf16x8 afr0[2][KS], afr1[2][KS];
    auto loadA2 = [&](int kc, bf16x8 (&af)[2][KS]) {
#pragma unroll
      for (int mi = 0; mi < 2; mi++)
#pragma unroll
        for (int ks = 0; ks < KS; ks++)
          af[mi][ks] = *(const bf16x8*)(aRow + (size_t)mi * 16 * K + kc * KT + ks * 32);
    };
    auto computeK = [&](int kc, bf16x8 (&af)[2][KS]) {
#pragma unroll
      for (int ch = 0; ch < NCH; ++ch)
#pragma unroll
        for (int ks = 0; ks < KS; ks++) {
          const int kb = kc * KS + ks;
          const bf16x8 b0 = loadB(ch, 0, kb);
          const bf16x8 b1 = loadB(ch, 1, kb);
#pragma unroll
          for (int mi = 0; mi < 2; mi++) {
            acc[ch][mi][0] = __builtin_amdgcn_mfma_f32_16x16x32_bf16(af[mi][ks], b0, acc[ch][mi][0], 0, 0, 0);
            acc[ch][mi][1] = __builtin_amdgcn_mfma_f32_16x16x32_bf16(af[mi][ks], b1, acc[ch][mi][1], 0, 0, 0);
          }
        }
    };

    loadA2(0, afr0);
#pragma unroll 1
    for (int kc = 0; kc < KCH; kc += 2) {
      if (kc + 1 < KCH) loadA2(kc + 1, afr1);
      computeK(kc, afr0);
      if (kc + 2 < KCH) loadA2(kc + 2, afr0);
      if (kc + 1 < KCH) computeK(kc + 1, afr1);
    }
#pragma unroll
    for (int ch = 0; ch < NCH; ++ch) epilogue(acc[ch], ch);
  }
}

// ---------------------------------------------------------------------------
extern "C" void kernel_launch(void* const* d_in, const int* in_sizes, int n_in,
                              void* d_out, int out_size, void* d_ws, size_t ws_size,
                              hipStream_t stream) {
  const float* x    = (const float*)d_in[0];
  const float* wq   = (const float*)d_in[1];
  const float* bq   = (const float*)d_in[2];
  const float* wk   = (const float*)d_in[3];
  const float* bk   = (const float*)d_in[4];
  const float* wv   = (const float*)d_in[5];
  const float* bv   = (const float*)d_in[6];
  const float* ln1g = (const float*)d_in[7];
  const float* ln1b = (const float*)d_in[8];
  const float* ln2g = (const float*)d_in[9];
  const float* ln2b = (const float*)d_in[10];
  const float* fc1w = (const float*)d_in[11];
  const float* fc1b = (const float*)d_in[12];
  const float* fc2w = (const float*)d_in[13];
  const float* fc2b = (const float*)d_in[14];
  float* out = (float*)d_out;

  // Workspace (aliased by liveness), total ~225.4 MB:
  //   [0,64)    x1 fp32                (res_ln2 -> fc2)
  //   [64,192)  h bf16 [N,1024]        (fc1 -> fc2); overlays:
  //     [64,160)  qkv bf16 [N,768]     (qkv-gemm -> attn)
  //     [160,192) n1 / attn bf16       (ln1 -> qkv-gemm; attn -> res_ln2)
  //   [192,224) n2 bf16                (res_ln2 -> fc1)
  //   [224,..)  fragment-major bf16 weights + fused bias
  char* ws = (char*)d_ws;
  const size_t MB = (size_t)1 << 20;
  float* x1   = (float*)(ws);
  u16* qkv    = (u16*)(ws + 64 * MB);
  u16* hbuf   = (u16*)(ws + 64 * MB);
  u16* n1     = (u16*)(ws + 160 * MB);
  u16* attnb  = n1;
  u16* n2     = (u16*)(ws + 192 * MB);
  u16* wqkvF  = (u16*)(ws + 224 * MB);      // frag-major [768 cols x 256 k]
  u16* f1F    = wqkvF + 768 * 256;          // frag-major [1024 cols x 256 k]
  u16* f2F    = f1F + 1024 * 256;           // frag-major [256 cols x 1024 k]
  float* bqkv = (float*)(f2F + 256 * 1024); // [768]

  dim3 blk(256);
  // weight prep: src w is [K_in, N_out] row-major fp32.
  // Each 256x256 weight: 16 groups x 8 kb = 128 units -> 32 blocks;
  // per-weight stride in the blob = 128 units * 512 u16 = 65536 u16.
  wfrag_kernel<<<dim3(32),  blk, 0, stream>>>(wq,   wqkvF,          256, 256);
  wfrag_kernel<<<dim3(32),  blk, 0, stream>>>(wk,   wqkvF + 65536,  256, 256);  // groups 16..31
  wfrag_kernel<<<dim3(32),  blk, 0, stream>>>(wv,   wqkvF + 131072, 256, 256);  // groups 32..47
  wfrag_kernel<<<dim3(128), blk, 0, stream>>>(fc1w, f1F, 1024, 256);   // 64 g x 8 kb = 512 units
  wfrag_kernel<<<dim3(128), blk, 0, stream>>>(fc2w, f2F, 256, 1024);   // 16 g x 32 kb = 512 units
  concat_bias_kernel<<<dim3(3), blk, 0, stream>>>(bq, bk, bv, bqkv);

  ln1_kernel<<<NPIX / 32, blk, 0, stream>>>(x, ln1g, ln1b, n1);

  // fused QKV: [N,256] x frag(768,256) -> qkv [N,768]
  gemm_regB<12, 1, 256, 0><<<dim3(NPIX / 64), blk, 0, stream>>>(
      n1, wqkvF, bqkv, nullptr, qkv, nullptr);

  attn_kernel<<<NPIX / 4, blk, 0, stream>>>(qkv, attnb);

  res_ln2_kernel<<<NPIX / 32, blk, 0, stream>>>(x, attnb, ln2g, ln2b, x1, n2);

  // fc1 + gelu: [N,256] x frag(1024,256) -> h [N,1024]
  gemm_regB<16, 1, 256, 1><<<dim3(NPIX / 64), blk, 0, stream>>>(
      n2, f1F, fc1b, nullptr, hbuf, nullptr);

  // fc2 + residual + transpose: [N,1024] x frag(256,1024) -> out [B,C,H,W]
  gemm_regB<4, 8, 128, 2><<<dim3(NPIX / 64), blk, 0, stream>>>(
      hbuf, f2F, fc2b, x1, nullptr, out);
}

// Round 6
// 509.991 us; speedup vs baseline: 1.0476x; 1.0086x over previous
//
#include <hip/hip_runtime.h>
#include <hip/hip_bf16.h>
#include <math.h>

// Problem constants: B=4, C=D=256, H=W=128, HID=1024, N = B*H*W = 65536.
#define NPIX  65536
#define CCH   256
#define HWSZ  16384
#define WIDTH 128
#define HID   1024

typedef unsigned short u16;
typedef __bf16 bf16x8 __attribute__((ext_vector_type(8)));
typedef float  floatx4 __attribute__((ext_vector_type(4)));

__device__ __forceinline__ float bf2f(u16 u) {
  union { unsigned int i; float f; } c; c.i = ((unsigned int)u) << 16; return c.f;
}
__device__ __forceinline__ float bflo(unsigned int u) {
  union { unsigned int i; float f; } c; c.i = u << 16; return c.f;
}
__device__ __forceinline__ float bfhi(unsigned int u) {
  union { unsigned int i; float f; } c; c.i = u & 0xffff0000u; return c.f;
}
__device__ __forceinline__ u16 f2bf(float f) {
  union { float f; unsigned int i; } c; c.f = f;
  unsigned int x = c.i;
  x += 0x7fffu + ((x >> 16) & 1u);   // round-to-nearest-even
  return (u16)(x >> 16);
}
__device__ __forceinline__ float gelu_tanh(float val) {
  const float t = 0.7978845608028654f * (val + 0.044715f * val * val * val);
  const float e = __expf(2.0f * t);
  const float th = 1.0f - 2.0f / (e + 1.0f);   // tanh, inf-safe
  return 0.5f * val * (1.0f + th);
}

// ---------------------------------------------------------------------------
// Weight fp32 [K,N] -> fragment-major bf16 blob:
// unit u = g*(K/32) + kb   (g = 16-col group, kb = 32-k block); unit = 512 u16.
// dst[u*512 + lane*8 + e] = bf16(src[(kb*32 + (lane>>4)*8 + e)*N + g*16 + (lane&15)])
// A wave's MFMA B-fragment load is then one coalesced 1KB global_load_dwordx4.
__global__ __launch_bounds__(256) void wfrag_kernel(
    const float* __restrict__ src, u16* __restrict__ dst, int N, int K) {
  const int tid = threadIdx.x;
  const int u = blockIdx.x * 4 + (tid >> 6);
  const int lane = tid & 63, quad = lane >> 4, l16 = lane & 15;
  const int K32 = K >> 5;
  const int g = u / K32, kb = u - g * K32;
  const int n = g * 16 + l16;
  const int k0 = kb * 32 + quad * 8;
  u16 tmp[8];
#pragma unroll
  for (int e = 0; e < 8; e++) tmp[e] = f2bf(src[(size_t)(k0 + e) * N + n]);
  *(bf16x8*)(dst + ((size_t)u * 64 + lane) * 8) = *(bf16x8*)tmp;
}

__global__ __launch_bounds__(256) void concat_bias_kernel(
    const float* __restrict__ bq, const float* __restrict__ bk,
    const float* __restrict__ bv, float* __restrict__ dst) {
  const int i = blockIdx.x * 256 + threadIdx.x;   // grid 3
  if (i < 256) dst[i] = bq[i];
  else if (i < 512) dst[i] = bk[i - 256];
  else if (i < 768) dst[i] = bv[i - 512];
}

// ---------------------------------------------------------------------------
// LayerNorm1: x [B,C,H,W] fp32 -> n1 [N,256] bf16
__global__ __launch_bounds__(256) void ln1_kernel(
    const float* __restrict__ x, const float* __restrict__ g,
    const float* __restrict__ bb, u16* __restrict__ n1) {
  __shared__ float sx[32][257];
  __shared__ float sred[16][32];
  __shared__ float sm[32], sr[32];
  const int tx = threadIdx.x;
  const int p0 = blockIdx.x * 32;
  {
    const int pix = tx & 31, cpart = tx >> 5;
    const int p = p0 + pix;
    const int b = p >> 14, hw = p & (HWSZ - 1);
    const float* xb = x + ((size_t)b * CCH) * HWSZ + hw;
    float s = 0.f, s2 = 0.f;
#pragma unroll 4
    for (int i = 0; i < 32; i++) {
      const int c = cpart * 32 + i;
      const float v = xb[(size_t)c * HWSZ];
      sx[pix][c] = v;
      s += v; s2 += v * v;
    }
    sred[cpart][pix] = s; sred[8 + cpart][pix] = s2;
  }
  __syncthreads();
  if (tx < 32) {
    float s = 0.f, s2 = 0.f;
#pragma unroll
    for (int j = 0; j < 8; j++) { s += sred[j][tx]; s2 += sred[8 + j][tx]; }
    const float m = s * (1.0f / 256.0f);
    const float var = s2 * (1.0f / 256.0f) - m * m;
    sm[tx] = m; sr[tx] = rsqrtf(var + 1e-5f);
  }
  __syncthreads();
  const float gc = g[tx], bc = bb[tx];
#pragma unroll 4
  for (int i = 0; i < 32; i++) {
    const float v = (sx[i][tx] - sm[i]) * sr[i] * gc + bc;
    n1[(size_t)(p0 + i) * CCH + tx] = f2bf(v);
  }
}

// ---------------------------------------------------------------------------
// Residual + LayerNorm2: x1 = x + attn (fp32 out), n2 = LN(x1) bf16
__global__ __launch_bounds__(256) void res_ln2_kernel(
    const float* __restrict__ x, const u16* __restrict__ attn,
    const float* __restrict__ g, const float* __restrict__ bb,
    float* __restrict__ x1, u16* __restrict__ n2) {
  __shared__ float sx[32][257];
  __shared__ float sred[16][32];
  __shared__ float sm[32], sr[32];
  const int tx = threadIdx.x;
  const int p0 = blockIdx.x * 32;
  {
    const int pix = tx & 31, cpart = tx >> 5;
    const int p = p0 + pix;
    const int b = p >> 14, hw = p & (HWSZ - 1);
    const float* xb = x + ((size_t)b * CCH) * HWSZ + hw;
#pragma unroll 4
    for (int i = 0; i < 32; i++) {
      const int c = cpart * 32 + i;
      sx[pix][c] = xb[(size_t)c * HWSZ];
    }
  }
  __syncthreads();
#pragma unroll 4
  for (int i = 0; i < 32; i++) {
    const float v = sx[i][tx] + bf2f(attn[(size_t)(p0 + i) * CCH + tx]);
    sx[i][tx] = v;
    x1[(size_t)(p0 + i) * CCH + tx] = v;
  }
  __syncthreads();
  {
    const int pix = tx & 31, cpart = tx >> 5;
    float s = 0.f, s2 = 0.f;
#pragma unroll 4
    for (int i = 0; i < 32; i++) {
      const float v = sx[pix][cpart * 32 + i];
      s += v; s2 += v * v;
    }
    sred[cpart][pix] = s; sred[8 + cpart][pix] = s2;
  }
  __syncthreads();
  if (tx < 32) {
    float s = 0.f, s2 = 0.f;
#pragma unroll
    for (int j = 0; j < 8; j++) { s += sred[j][tx]; s2 += sred[8 + j][tx]; }
    const float m = s * (1.0f / 256.0f);
    const float var = s2 * (1.0f / 256.0f) - m * m;
    sm[tx] = m; sr[tx] = rsqrtf(var + 1e-5f);
  }
  __syncthreads();
  const float gc = g[tx], bc = bb[tx];
#pragma unroll 4
  for (int i = 0; i < 32; i++) {
    const float v = (sx[i][tx] - sm[i]) * sr[i] * gc + bc;
    n2[(size_t)(p0 + i) * CCH + tx] = f2bf(v);
  }
}

// ---------------------------------------------------------------------------
// 3x3 neighborhood attention over fused qkv [N,768] (q|k|v per row).
__global__ __launch_bounds__(256) void attn_kernel(
    const u16* __restrict__ qkv, u16* __restrict__ attn) {
  const int tid = threadIdx.x;
  const int wave = tid >> 6, lane = tid & 63;
  const int p = blockIdx.x * 4 + wave;
  const int hw = p & (HWSZ - 1);
  const int hh = hw >> 7, ww = hw & (WIDTH - 1);
  const u16* rowp = qkv + (size_t)p * 768 + lane * 4;
  const uint2 qr = *(const uint2*)rowp;
  const float qf0 = bflo(qr.x), qf1 = bfhi(qr.x);
  const float qf2 = bflo(qr.y), qf3 = bfhi(qr.y);
  float sc[9];
#pragma unroll
  for (int n = 0; n < 9; n++) {
    const int dy = n / 3 - 1, dx = n % 3 - 1;
    const int y = hh + dy, x2 = ww + dx;
    float s = -1e30f;
    if (y >= 0 && y < 128 && x2 >= 0 && x2 < 128) {   // wave-uniform branch
      const uint2 kr = *(const uint2*)(rowp + 256 + (dy * WIDTH + dx) * 768);
      float d = qf0 * bflo(kr.x) + qf1 * bfhi(kr.x)
              + qf2 * bflo(kr.y) + qf3 * bfhi(kr.y);
#pragma unroll
      for (int o = 32; o >= 1; o >>= 1) d += __shfl_xor(d, o, 64);
      s = d * 0.0625f;   // 1/sqrt(256)
    }
    sc[n] = s;
  }
  float mx = sc[0];
#pragma unroll
  for (int n = 1; n < 9; n++) mx = fmaxf(mx, sc[n]);
  float wgt[9], wsum = 0.f;
#pragma unroll
  for (int n = 0; n < 9; n++) { wgt[n] = __expf(sc[n] - mx); wsum += wgt[n]; }
  const float inv = 1.0f / wsum;
  float a0 = 0.f, a1 = 0.f, a2 = 0.f, a3 = 0.f;
#pragma unroll
  for (int n = 0; n < 9; n++) {
    const int dy = n / 3 - 1, dx = n % 3 - 1;
    const int y = hh + dy, x2 = ww + dx;
    if (y >= 0 && y < 128 && x2 >= 0 && x2 < 128) {
      const uint2 vr = *(const uint2*)(rowp + 512 + (dy * WIDTH + dx) * 768);
      const float wn = wgt[n] * inv;
      a0 += wn * bflo(vr.x); a1 += wn * bfhi(vr.x);
      a2 += wn * bflo(vr.y); a3 += wn * bfhi(vr.y);
    }
  }
  uint2 o;
  o.x = ((unsigned int)f2bf(a1) << 16) | (unsigned int)f2bf(a0);
  o.y = ((unsigned int)f2bf(a3) << 16) | (unsigned int)f2bf(a2);
  *(uint2*)(attn + (size_t)p * CCH + lane * 4) = o;
}

// ---------------------------------------------------------------------------
// Barrier-free register GEMM for QKV: 64-row tiles, 4 waves 2x2 over 32x32.
// A (n1) fragments resident in VGPRs (bound=3 -> 170 VGPR cap; afr=64).
// B from L2-resident fragment blob, one dwordx4 per fragment.
__global__ __launch_bounds__(256, 3) void qkv_kernel(
    const u16* __restrict__ A, const u16* __restrict__ wf,
    const float* __restrict__ bias, u16* __restrict__ outb) {
  const int tid  = threadIdx.x;
  const int wave = tid >> 6, lane = tid & 63;
  const int quad = lane >> 4, l16 = lane & 15;
  const int m0  = blockIdx.x * 64;
  const int wr  = (wave & 1) * 32;
  const int wcq = (wave >> 1) * 32;
  const int w2  = (wave >> 1) * 2;   // base 16-col group within a 64-col chunk

  const u16* aRow = A + (size_t)(m0 + wr + l16) * CCH + quad * 8;
  bf16x8 afr[2][8];
#pragma unroll
  for (int mi = 0; mi < 2; mi++)
#pragma unroll
    for (int ks = 0; ks < 8; ks++)
      afr[mi][ks] = *(const bf16x8*)(aRow + (size_t)mi * 16 * CCH + ks * 32);

#pragma unroll 1
  for (int ch = 0; ch < 12; ++ch) {
    floatx4 acc[2][2];
#pragma unroll
    for (int mi = 0; mi < 2; mi++)
#pragma unroll
      for (int ni = 0; ni < 2; ni++) acc[mi][ni] = (floatx4){0.f, 0.f, 0.f, 0.f};
#pragma unroll
    for (int ks = 0; ks < 8; ks++) {
      const bf16x8 b0 = *(const bf16x8*)(wf + (((size_t)(ch * 4 + w2) * 8 + ks) << 9) + (lane << 3));
      const bf16x8 b1 = *(const bf16x8*)(wf + (((size_t)(ch * 4 + w2 + 1) * 8 + ks) << 9) + (lane << 3));
#pragma unroll
      for (int mi = 0; mi < 2; mi++) {
        acc[mi][0] = __builtin_amdgcn_mfma_f32_16x16x32_bf16(afr[mi][ks], b0, acc[mi][0], 0, 0, 0);
        acc[mi][1] = __builtin_amdgcn_mfma_f32_16x16x32_bf16(afr[mi][ks], b1, acc[mi][1], 0, 0, 0);
      }
    }
#pragma unroll
    for (int mi = 0; mi < 2; mi++)
#pragma unroll
      for (int ni = 0; ni < 2; ni++) {
        const int col = ch * 64 + wcq + ni * 16 + l16;
        const float bs = bias[col];
        const int row0 = m0 + wr + mi * 16 + quad * 4;
#pragma unroll
        for (int r = 0; r < 4; r++)
          outb[(size_t)(row0 + r) * 768 + col] = f2bf(acc[mi][ni][r] + bs);
      }
  }
}

// ---------------------------------------------------------------------------
// Fused MLP: out = x1 + (gelu(n2 @ W1 + b1) @ W2 + b2), transposed store.
// 32-row blocks (grid 2048). h [32 x 1024] bf16 lives in LDS (row stride
// 1032 u16 = 2064 B -> 16B-aligned rows, uniform bank coverage for b128
// reads). One barrier between fc1-write and fc2-read. Weights from
// L2-resident fragment blobs. A fragments resident in VGPRs (bound=2).
#define HP 1032
__global__ __launch_bounds__(256, 2) void mlp_kernel(
    const u16* __restrict__ n2, const u16* __restrict__ f1F,
    const u16* __restrict__ f2F, const float* __restrict__ b1,
    const float* __restrict__ b2, const float* __restrict__ x1,
    float* __restrict__ out) {
  __shared__ u16 h[32 * HP];
  const int tid  = threadIdx.x;
  const int wave = tid >> 6, lane = tid & 63;
  const int quad = lane >> 4, l16 = lane & 15;
  const int p0 = blockIdx.x * 32;

  // ---- fc1 + GELU: wave computes h cols [wave*256, wave*256+256)
  const u16* aRow = n2 + (size_t)(p0 + l16) * CCH + quad * 8;
  bf16x8 afr[2][8];
#pragma unroll
  for (int mi = 0; mi < 2; mi++)
#pragma unroll
    for (int kb = 0; kb < 8; kb++)
      afr[mi][kb] = *(const bf16x8*)(aRow + (size_t)mi * 16 * CCH + kb * 32);

#pragma unroll 2
  for (int g = 0; g < 16; g++) {
    const int gg = wave * 16 + g;
    floatx4 acc0 = (floatx4){0.f, 0.f, 0.f, 0.f};
    floatx4 acc1 = (floatx4){0.f, 0.f, 0.f, 0.f};
#pragma unroll
    for (int kb = 0; kb < 8; kb++) {
      const bf16x8 b = *(const bf16x8*)(f1F + (((size_t)gg * 8 + kb) << 9) + (lane << 3));
      acc0 = __builtin_amdgcn_mfma_f32_16x16x32_bf16(afr[0][kb], b, acc0, 0, 0, 0);
      acc1 = __builtin_amdgcn_mfma_f32_16x16x32_bf16(afr[1][kb], b, acc1, 0, 0, 0);
    }
    const int col = gg * 16 + l16;
    const float bs = b1[col];
#pragma unroll
    for (int r = 0; r < 4; r++) {
      const int rr = quad * 4 + r;
      h[rr * HP + col]        = f2bf(gelu_tanh(acc0[r] + bs));
      h[(16 + rr) * HP + col] = f2bf(gelu_tanh(acc1[r] + bs));
    }
  }
  __syncthreads();

  // ---- fc2 + bias + residual + transposed store: wave cols [wave*64, +64)
  floatx4 acc[4][2];
#pragma unroll
  for (int gi = 0; gi < 4; gi++)
#pragma unroll
    for (int mi = 0; mi < 2; mi++) acc[gi][mi] = (floatx4){0.f, 0.f, 0.f, 0.f};

#pragma unroll 4
  for (int kb = 0; kb < 32; kb++) {
    const bf16x8 a0 = *(const bf16x8*)&h[l16 * HP + kb * 32 + quad * 8];
    const bf16x8 a1 = *(const bf16x8*)&h[(16 + l16) * HP + kb * 32 + quad * 8];
#pragma unroll
    for (int gi = 0; gi < 4; gi++) {
      const bf16x8 b = *(const bf16x8*)(f2F + (((size_t)(wave * 4 + gi) * 32 + kb) << 9) + (lane << 3));
      acc[gi][0] = __builtin_amdgcn_mfma_f32_16x16x32_bf16(a0, b, acc[gi][0], 0, 0, 0);
      acc[gi][1] = __builtin_amdgcn_mfma_f32_16x16x32_bf16(a1, b, acc[gi][1], 0, 0, 0);
    }
  }

#pragma unroll
  for (int gi = 0; gi < 4; gi++)
#pragma unroll
    for (int mi = 0; mi < 2; mi++) {
      const int col = wave * 64 + gi * 16 + l16;
      const float bs = b2[col];
      const int row0 = p0 + mi * 16 + quad * 4;
      floatx4 vv;
#pragma unroll
      for (int r = 0; r < 4; r++)
        vv[r] = acc[gi][mi][r] + bs + x1[(size_t)(row0 + r) * CCH + col];
      *(floatx4*)&out[((size_t)((row0 >> 14) * CCH + col)) * HWSZ + (row0 & (HWSZ - 1))] = vv;
    }
}

// ---------------------------------------------------------------------------
extern "C" void kernel_launch(void* const* d_in, const int* in_sizes, int n_in,
                              void* d_out, int out_size, void* d_ws, size_t ws_size,
                              hipStream_t stream) {
  const float* x    = (const float*)d_in[0];
  const float* wq   = (const float*)d_in[1];
  const float* bq   = (const float*)d_in[2];
  const float* wk   = (const float*)d_in[3];
  const float* bk   = (const float*)d_in[4];
  const float* wv   = (const float*)d_in[5];
  const float* bv   = (const float*)d_in[6];
  const float* ln1g = (const float*)d_in[7];
  const float* ln1b = (const float*)d_in[8];
  const float* ln2g = (const float*)d_in[9];
  const float* ln2b = (const float*)d_in[10];
  const float* fc1w = (const float*)d_in[11];
  const float* fc1b = (const float*)d_in[12];
  const float* fc2w = (const float*)d_in[13];
  const float* fc2b = (const float*)d_in[14];
  float* out = (float*)d_out;

  // Workspace (aliased by liveness):
  //   [0,64)    x1 fp32                (res_ln2 -> mlp)
  //   [64,160)  qkv bf16 [N,768]       (qkv-gemm -> attn)
  //   [160,192) n1 / attn bf16         (ln1 -> qkv-gemm; attn -> res_ln2)
  //   [192,224) n2 bf16                (res_ln2 -> mlp)
  //   [224,..)  fragment-major bf16 weights + fused bias
  char* ws = (char*)d_ws;
  const size_t MB = (size_t)1 << 20;
  float* x1   = (float*)(ws);
  u16* qkv    = (u16*)(ws + 64 * MB);
  u16* n1     = (u16*)(ws + 160 * MB);
  u16* attnb  = n1;
  u16* n2     = (u16*)(ws + 192 * MB);
  u16* wqkvF  = (u16*)(ws + 224 * MB);      // frag-major [768 cols x 256 k]
  u16* f1F    = wqkvF + 768 * 256;          // frag-major [1024 cols x 256 k]
  u16* f2F    = f1F + 1024 * 256;           // frag-major [256 cols x 1024 k]
  float* bqkv = (float*)(f2F + 256 * 1024); // [768]

  dim3 blk(256);
  // weight prep: src w is [K_in, N_out] row-major fp32.
  // 256x256 weight: 16 g x 8 kb = 128 units -> 32 blocks; blob stride 65536 u16.
  wfrag_kernel<<<dim3(32),  blk, 0, stream>>>(wq,   wqkvF,          256, 256);
  wfrag_kernel<<<dim3(32),  blk, 0, stream>>>(wk,   wqkvF + 65536,  256, 256);
  wfrag_kernel<<<dim3(32),  blk, 0, stream>>>(wv,   wqkvF + 131072, 256, 256);
  wfrag_kernel<<<dim3(128), blk, 0, stream>>>(fc1w, f1F, 1024, 256);   // 64 g x 8 kb
  wfrag_kernel<<<dim3(128), blk, 0, stream>>>(fc2w, f2F, 256, 1024);   // 16 g x 32 kb
  concat_bias_kernel<<<dim3(3), blk, 0, stream>>>(bq, bk, bv, bqkv);

  ln1_kernel<<<NPIX / 32, blk, 0, stream>>>(x, ln1g, ln1b, n1);

  // fused QKV: [N,256] x frag(768,256) -> qkv [N,768]
  qkv_kernel<<<dim3(NPIX / 64), blk, 0, stream>>>(n1, wqkvF, bqkv, qkv);

  attn_kernel<<<NPIX / 4, blk, 0, stream>>>(qkv, attnb);

  res_ln2_kernel<<<NPIX / 32, blk, 0, stream>>>(x, attnb, ln2g, ln2b, x1, n2);

  // fused MLP: fc1 + gelu + fc2 + residual + transpose
  mlp_kernel<<<dim3(NPIX / 32), blk, 0, stream>>>(
      n2, f1F, f2F, fc1b, fc2b, x1, out);
}

// Round 7
// 482.437 us; speedup vs baseline: 1.1074x; 1.0571x over previous
//
#include <hip/hip_runtime.h>
#include <hip/hip_bf16.h>
#include <math.h>

// Problem constants: B=4, C=D=256, H=W=128, HID=1024, N = B*H*W = 65536.
#define NPIX  65536
#define CCH   256
#define HWSZ  16384
#define WIDTH 128
#define HID   1024

typedef unsigned short u16;
typedef __bf16 bf16x8 __attribute__((ext_vector_type(8)));
typedef float  floatx4 __attribute__((ext_vector_type(4)));

__device__ __forceinline__ float bf2f(u16 u) {
  union { unsigned int i; float f; } c; c.i = ((unsigned int)u) << 16; return c.f;
}
__device__ __forceinline__ float bflo(unsigned int u) {
  union { unsigned int i; float f; } c; c.i = u << 16; return c.f;
}
__device__ __forceinline__ float bfhi(unsigned int u) {
  union { unsigned int i; float f; } c; c.i = u & 0xffff0000u; return c.f;
}
__device__ __forceinline__ u16 f2bf(float f) {
  union { float f; unsigned int i; } c; c.f = f;
  unsigned int x = c.i;
  x += 0x7fffu + ((x >> 16) & 1u);   // round-to-nearest-even
  return (u16)(x >> 16);
}
__device__ __forceinline__ float gelu_tanh(float val) {
  const float t = 0.7978845608028654f * (val + 0.044715f * val * val * val);
  const float e = __expf(2.0f * t);
  const float th = 1.0f - 2.0f / (e + 1.0f);   // tanh, inf-safe
  return 0.5f * val * (1.0f + th);
}

// async global->LDS, 16B per lane; LDS dest is wave-uniform base + lane*16.
__device__ __forceinline__ void async16(const void* g, void* l) {
  __builtin_amdgcn_global_load_lds(
      (const __attribute__((address_space(1))) void*)g,
      (__attribute__((address_space(3))) void*)l, 16, 0, 0);
}

// ---------------------------------------------------------------------------
// Weight fp32 [K,N] -> fragment-major bf16 blob:
// unit u = g*(K/32) + kb   (g = 16-col group, kb = 32-k block); unit = 512 u16.
// dst[u*512 + lane*8 + e] = bf16(src[(kb*32 + (lane>>4)*8 + e)*N + g*16 + (lane&15)])
__global__ __launch_bounds__(256) void wfrag_kernel(
    const float* __restrict__ src, u16* __restrict__ dst, int N, int K) {
  const int tid = threadIdx.x;
  const int u = blockIdx.x * 4 + (tid >> 6);
  const int lane = tid & 63, quad = lane >> 4, l16 = lane & 15;
  const int K32 = K >> 5;
  const int g = u / K32, kb = u - g * K32;
  const int n = g * 16 + l16;
  const int k0 = kb * 32 + quad * 8;
  u16 tmp[8];
#pragma unroll
  for (int e = 0; e < 8; e++) tmp[e] = f2bf(src[(size_t)(k0 + e) * N + n]);
  *(bf16x8*)(dst + ((size_t)u * 64 + lane) * 8) = *(bf16x8*)tmp;
}

__global__ __launch_bounds__(256) void concat_bias_kernel(
    const float* __restrict__ bq, const float* __restrict__ bk,
    const float* __restrict__ bv, float* __restrict__ dst) {
  const int i = blockIdx.x * 256 + threadIdx.x;   // grid 3
  if (i < 256) dst[i] = bq[i];
  else if (i < 512) dst[i] = bk[i - 256];
  else if (i < 768) dst[i] = bv[i - 512];
}

// ---------------------------------------------------------------------------
// LayerNorm1: x [B,C,H,W] fp32 -> n1 [N,256] bf16
__global__ __launch_bounds__(256) void ln1_kernel(
    const float* __restrict__ x, const float* __restrict__ g,
    const float* __restrict__ bb, u16* __restrict__ n1) {
  __shared__ float sx[32][257];
  __shared__ float sred[16][32];
  __shared__ float sm[32], sr[32];
  const int tx = threadIdx.x;
  const int p0 = blockIdx.x * 32;
  {
    const int pix = tx & 31, cpart = tx >> 5;
    const int p = p0 + pix;
    const int b = p >> 14, hw = p & (HWSZ - 1);
    const float* xb = x + ((size_t)b * CCH) * HWSZ + hw;
    float s = 0.f, s2 = 0.f;
#pragma unroll 4
    for (int i = 0; i < 32; i++) {
      const int c = cpart * 32 + i;
      const float v = xb[(size_t)c * HWSZ];
      sx[pix][c] = v;
      s += v; s2 += v * v;
    }
    sred[cpart][pix] = s; sred[8 + cpart][pix] = s2;
  }
  __syncthreads();
  if (tx < 32) {
    float s = 0.f, s2 = 0.f;
#pragma unroll
    for (int j = 0; j < 8; j++) { s += sred[j][tx]; s2 += sred[8 + j][tx]; }
    const float m = s * (1.0f / 256.0f);
    const float var = s2 * (1.0f / 256.0f) - m * m;
    sm[tx] = m; sr[tx] = rsqrtf(var + 1e-5f);
  }
  __syncthreads();
  const float gc = g[tx], bc = bb[tx];
#pragma unroll 4
  for (int i = 0; i < 32; i++) {
    const float v = (sx[i][tx] - sm[i]) * sr[i] * gc + bc;
    n1[(size_t)(p0 + i) * CCH + tx] = f2bf(v);
  }
}

// ---------------------------------------------------------------------------
// Residual + LayerNorm2: x1 = x + attn (fp32 out), n2 = LN(x1) bf16
__global__ __launch_bounds__(256) void res_ln2_kernel(
    const float* __restrict__ x, const u16* __restrict__ attn,
    const float* __restrict__ g, const float* __restrict__ bb,
    float* __restrict__ x1, u16* __restrict__ n2) {
  __shared__ float sx[32][257];
  __shared__ float sred[16][32];
  __shared__ float sm[32], sr[32];
  const int tx = threadIdx.x;
  const int p0 = blockIdx.x * 32;
  {
    const int pix = tx & 31, cpart = tx >> 5;
    const int p = p0 + pix;
    const int b = p >> 14, hw = p & (HWSZ - 1);
    const float* xb = x + ((size_t)b * CCH) * HWSZ + hw;
#pragma unroll 4
    for (int i = 0; i < 32; i++) {
      const int c = cpart * 32 + i;
      sx[pix][c] = xb[(size_t)c * HWSZ];
    }
  }
  __syncthreads();
#pragma unroll 4
  for (int i = 0; i < 32; i++) {
    const float v = sx[i][tx] + bf2f(attn[(size_t)(p0 + i) * CCH + tx]);
    sx[i][tx] = v;
    x1[(size_t)(p0 + i) * CCH + tx] = v;
  }
  __syncthreads();
  {
    const int pix = tx & 31, cpart = tx >> 5;
    float s = 0.f, s2 = 0.f;
#pragma unroll 4
    for (int i = 0; i < 32; i++) {
      const float v = sx[pix][cpart * 32 + i];
      s += v; s2 += v * v;
    }
    sred[cpart][pix] = s; sred[8 + cpart][pix] = s2;
  }
  __syncthreads();
  if (tx < 32) {
    float s = 0.f, s2 = 0.f;
#pragma unroll
    for (int j = 0; j < 8; j++) { s += sred[j][tx]; s2 += sred[8 + j][tx]; }
    const float m = s * (1.0f / 256.0f);
    const float var = s2 * (1.0f / 256.0f) - m * m;
    sm[tx] = m; sr[tx] = rsqrtf(var + 1e-5f);
  }
  __syncthreads();
  const float gc = g[tx], bc = bb[tx];
#pragma unroll 4
  for (int i = 0; i < 32; i++) {
    const float v = (sx[i][tx] - sm[i]) * sr[i] * gc + bc;
    n2[(size_t)(p0 + i) * CCH + tx] = f2bf(v);
  }
}

// ---------------------------------------------------------------------------
// 3x3 neighborhood attention over fused qkv [N,768] (q|k|v per row).
__global__ __launch_bounds__(256) void attn_kernel(
    const u16* __restrict__ qkv, u16* __restrict__ attn) {
  const int tid = threadIdx.x;
  const int wave = tid >> 6, lane = tid & 63;
  const int p = blockIdx.x * 4 + wave;
  const int hw = p & (HWSZ - 1);
  const int hh = hw >> 7, ww = hw & (WIDTH - 1);
  const u16* rowp = qkv + (size_t)p * 768 + lane * 4;
  const uint2 qr = *(const uint2*)rowp;
  const float qf0 = bflo(qr.x), qf1 = bfhi(qr.x);
  const float qf2 = bflo(qr.y), qf3 = bfhi(qr.y);
  float sc[9];
#pragma unroll
  for (int n = 0; n < 9; n++) {
    const int dy = n / 3 - 1, dx = n % 3 - 1;
    const int y = hh + dy, x2 = ww + dx;
    float s = -1e30f;
    if (y >= 0 && y < 128 && x2 >= 0 && x2 < 128) {   // wave-uniform branch
      const uint2 kr = *(const uint2*)(rowp + 256 + (dy * WIDTH + dx) * 768);
      float d = qf0 * bflo(kr.x) + qf1 * bfhi(kr.x)
              + qf2 * bflo(kr.y) + qf3 * bfhi(kr.y);
#pragma unroll
      for (int o = 32; o >= 1; o >>= 1) d += __shfl_xor(d, o, 64);
      s = d * 0.0625f;   // 1/sqrt(256)
    }
    sc[n] = s;
  }
  float mx = sc[0];
#pragma unroll
  for (int n = 1; n < 9; n++) mx = fmaxf(mx, sc[n]);
  float wgt[9], wsum = 0.f;
#pragma unroll
  for (int n = 0; n < 9; n++) { wgt[n] = __expf(sc[n] - mx); wsum += wgt[n]; }
  const float inv = 1.0f / wsum;
  float a0 = 0.f, a1 = 0.f, a2 = 0.f, a3 = 0.f;
#pragma unroll
  for (int n = 0; n < 9; n++) {
    const int dy = n / 3 - 1, dx = n % 3 - 1;
    const int y = hh + dy, x2 = ww + dx;
    if (y >= 0 && y < 128 && x2 >= 0 && x2 < 128) {
      const uint2 vr = *(const uint2*)(rowp + 512 + (dy * WIDTH + dx) * 768);
      const float wn = wgt[n] * inv;
      a0 += wn * bflo(vr.x); a1 += wn * bfhi(vr.x);
      a2 += wn * bflo(vr.y); a3 += wn * bfhi(vr.y);
    }
  }
  uint2 o;
  o.x = ((unsigned int)f2bf(a1) << 16) | (unsigned int)f2bf(a0);
  o.y = ((unsigned int)f2bf(a3) << 16) | (unsigned int)f2bf(a2);
  *(uint2*)(attn + (size_t)p * CCH + lane * 4) = o;
}

// ---------------------------------------------------------------------------
// GEMM with B in double-buffered LDS (staged via global_load_lds) and whole-K
// A in registers. 128-row blocks (4 waves x 32 rows), K=256, 64-col chunks.
// Per chunk: 1 barrier, stage next 32KB overlapped with 256 block-MFMAs.
// LDS operand demand ~26 B/cyc/CU at MFMA-bound (B reused by 2 row-frags x
// 4 waves).  EPI 0: bf16(acc+bias), stride 768.  EPI 1: gelu, stride 1024.
template <int NCH, int NST, int EPI>
__global__ __launch_bounds__(256, 3) void gemm_blds(
    const u16* __restrict__ A, const u16* __restrict__ wf,
    const float* __restrict__ bias, u16* __restrict__ outb) {
  __shared__ u16 sB[2][16384];    // 2 x 32 KB (LDS caps at 2 blocks/CU)
  const int tid  = threadIdx.x;
  const int wave = tid >> 6, lane = tid & 63;
  const int quad = lane >> 4, l16 = lane & 15;
  const int m0 = blockIdx.x * 128 + wave * 32;

  // A fragments: rows m0..m0+31, full K=256. 64 VGPRs.
  const u16* aRow = A + (size_t)(m0 + l16) * CCH + quad * 8;
  bf16x8 afr[2][8];
#pragma unroll
  for (int mi = 0; mi < 2; mi++)
#pragma unroll
    for (int ks = 0; ks < 8; ks++)
      afr[mi][ks] = *(const bf16x8*)(aRow + (size_t)mi * 16 * CCH + ks * 32);

  auto stage = [&](int ch, int buf) {
    const u16* g = wf + (size_t)ch * 16384;    // chunk = 4 groups x 8 kb = 32 KB
#pragma unroll
    for (int i = 0; i < 8; i++)
      async16(g + i * 2048 + tid * 8, &sB[buf][i * 2048 + tid * 8]);
  };

  stage(0, 0);
#pragma unroll 1
  for (int ch = 0; ch < NCH; ++ch) {
    __syncthreads();   // stage(ch) visible; all waves done reading buf (ch+1)&1
    if (ch + 1 < NCH) stage(ch + 1, (ch + 1) & 1);
    const u16* sb = sB[ch & 1];
    floatx4 acc[2][4];
#pragma unroll
    for (int mi = 0; mi < 2; mi++)
#pragma unroll
      for (int gi = 0; gi < 4; gi++) acc[mi][gi] = (floatx4){0.f, 0.f, 0.f, 0.f};
#pragma unroll
    for (int ks = 0; ks < 8; ks++) {
      bf16x8 bfr[4];
#pragma unroll
      for (int gi = 0; gi < 4; gi++)
        bfr[gi] = *(const bf16x8*)&sb[(gi * 8 + ks) * 512 + lane * 8];
#pragma unroll
      for (int mi = 0; mi < 2; mi++)
#pragma unroll
        for (int gi = 0; gi < 4; gi++)
          acc[mi][gi] = __builtin_amdgcn_mfma_f32_16x16x32_bf16(
              afr[mi][ks], bfr[gi], acc[mi][gi], 0, 0, 0);
    }
#pragma unroll
    for (int mi = 0; mi < 2; mi++)
#pragma unroll
      for (int gi = 0; gi < 4; gi++) {
        const int col = ch * 64 + gi * 16 + l16;
        const float bs = bias[col];
        const int row0 = m0 + mi * 16 + quad * 4;
#pragma unroll
        for (int r = 0; r < 4; r++) {
          float val = acc[mi][gi][r] + bs;
          if constexpr (EPI == 1) val = gelu_tanh(val);
          outb[(size_t)(row0 + r) * NST + col] = f2bf(val);
        }
      }
  }
}

// ---------------------------------------------------------------------------
// fc2 + residual + transposed store. 128x128 blocks (grid bx: row=bx>>1,
// colhalf=bx&1), 4 waves 2x2 over 64x64. Streams K=1024 in 64-wide chunks;
// B chunk (128 cols x 64 k = 16 KB) double-buffered in LDS; A (h) fragments
// from HBM per chunk.
__global__ __launch_bounds__(256, 3) void fc2_kernel(
    const u16* __restrict__ h, const u16* __restrict__ f2F,
    const float* __restrict__ bias, const float* __restrict__ x1,
    float* __restrict__ out) {
  __shared__ u16 sB[2][8192];     // 2 x 16 KB
  const int tid  = threadIdx.x;
  const int wave = tid >> 6, lane = tid & 63;
  const int quad = lane >> 4, l16 = lane & 15;
  const int bx = blockIdx.x;
  const int m0 = (bx >> 1) * 128 + (wave & 1) * 64;
  const int nb = bx & 1;                   // which 128-col half of N=256
  const int wgi = (wave >> 1) * 4;         // wave's base 16-col group (local)

  const u16* aRow = h + (size_t)(m0 + l16) * HID + quad * 8;

  // stage: 16 KB = groups [nb*8, +8) x kb {kc*2, kc*2+1}; 1024 16B-slots.
  auto stage = [&](int kc, int buf) {
#pragma unroll
    for (int i = 0; i < 4; i++) {
      const int s = i * 256 + tid;         // 16B slot
      const int gl = s >> 7;               // wave-uniform (64-runs align)
      const int rem = s & 127;
      async16(f2F + (((size_t)(nb * 8 + gl) * 32 + kc * 2) << 9) + rem * 8,
              &sB[buf][s * 8]);
    }
  };

  floatx4 acc[4][4];
#pragma unroll
  for (int mi = 0; mi < 4; mi++)
#pragma unroll
    for (int gi = 0; gi < 4; gi++) acc[mi][gi] = (floatx4){0.f, 0.f, 0.f, 0.f};

  stage(0, 0);
#pragma unroll 1
  for (int kc = 0; kc < 16; ++kc) {
    bf16x8 afr[4][2];
#pragma unroll
    for (int mi = 0; mi < 4; mi++)
#pragma unroll
      for (int ks = 0; ks < 2; ks++)
        afr[mi][ks] = *(const bf16x8*)(aRow + (size_t)mi * 16 * HID + kc * 64 + ks * 32);
    __syncthreads();   // stage(kc) visible; all waves done with buf (kc+1)&1
    if (kc + 1 < 16) stage(kc + 1, (kc + 1) & 1);
    const u16* sb = sB[kc & 1];
#pragma unroll
    for (int ks = 0; ks < 2; ks++) {
      bf16x8 bfr[4];
#pragma unroll
      for (int gi = 0; gi < 4; gi++)
        bfr[gi] = *(const bf16x8*)&sb[((wgi + gi) * 2 + ks) * 512 + lane * 8];
#pragma unroll
      for (int mi = 0; mi < 4; mi++)
#pragma unroll
        for (int gi = 0; gi < 4; gi++)
          acc[mi][gi] = __builtin_amdgcn_mfma_f32_16x16x32_bf16(
              afr[mi][ks], bfr[gi], acc[mi][gi], 0, 0, 0);
    }
  }

#pragma unroll
  for (int mi = 0; mi < 4; mi++)
#pragma unroll
    for (int gi = 0; gi < 4; gi++) {
      const int col = nb * 128 + (wgi + gi) * 16 + l16;
      const float bs = bias[col];
      const int row0 = m0 + mi * 16 + quad * 4;
      floatx4 vv;
#pragma unroll
      for (int r = 0; r < 4; r++)
        vv[r] = acc[mi][gi][r] + bs + x1[(size_t)(row0 + r) * CCH + col];
      *(floatx4*)&out[((size_t)((row0 >> 14) * CCH + col)) * HWSZ + (row0 & (HWSZ - 1))] = vv;
    }
}

// ---------------------------------------------------------------------------
extern "C" void kernel_launch(void* const* d_in, const int* in_sizes, int n_in,
                              void* d_out, int out_size, void* d_ws, size_t ws_size,
                              hipStream_t stream) {
  const float* x    = (const float*)d_in[0];
  const float* wq   = (const float*)d_in[1];
  const float* bq   = (const float*)d_in[2];
  const float* wk   = (const float*)d_in[3];
  const float* bk   = (const float*)d_in[4];
  const float* wv   = (const float*)d_in[5];
  const float* bv   = (const float*)d_in[6];
  const float* ln1g = (const float*)d_in[7];
  const float* ln1b = (const float*)d_in[8];
  const float* ln2g = (const float*)d_in[9];
  const float* ln2b = (const float*)d_in[10];
  const float* fc1w = (const float*)d_in[11];
  const float* fc1b = (const float*)d_in[12];
  const float* fc2w = (const float*)d_in[13];
  const float* fc2b = (const float*)d_in[14];
  float* out = (float*)d_out;

  // Workspace (aliased by liveness), ~226 MB:
  //   [0,64)    x1 fp32               (res_ln2 -> fc2)
  //   [64,192)  h bf16 [N,1024]       (fc1 -> fc2); overlays:
  //     [64,160)  qkv bf16 [N,768]    (qkv-gemm -> attn)
  //     [160,192) n1 / attn bf16      (ln1 -> qkv; attn -> res_ln2)
  //   [192,224) n2 bf16               (res_ln2 -> fc1)
  //   [224,..)  fragment-major bf16 weights + fused bias
  char* ws = (char*)d_ws;
  const size_t MB = (size_t)1 << 20;
  float* x1   = (float*)(ws);
  u16* qkv    = (u16*)(ws + 64 * MB);
  u16* hbuf   = (u16*)(ws + 64 * MB);
  u16* n1     = (u16*)(ws + 160 * MB);
  u16* attnb  = n1;
  u16* n2     = (u16*)(ws + 192 * MB);
  u16* wqkvF  = (u16*)(ws + 224 * MB);      // frag-major [768 cols x 256 k]
  u16* f1F    = wqkvF + 768 * 256;          // frag-major [1024 cols x 256 k]
  u16* f2F    = f1F + 1024 * 256;           // frag-major [256 cols x 1024 k]
  float* bqkv = (float*)(f2F + 256 * 1024); // [768]

  dim3 blk(256);
  // weight prep: src w is [K_in, N_out] row-major fp32.
  // 256x256 weight: 16 g x 8 kb = 128 units -> 32 blocks; blob stride 65536 u16.
  wfrag_kernel<<<dim3(32),  blk, 0, stream>>>(wq,   wqkvF,          256, 256);
  wfrag_kernel<<<dim3(32),  blk, 0, stream>>>(wk,   wqkvF + 65536,  256, 256);
  wfrag_kernel<<<dim3(32),  blk, 0, stream>>>(wv,   wqkvF + 131072, 256, 256);
  wfrag_kernel<<<dim3(128), blk, 0, stream>>>(fc1w, f1F, 1024, 256);   // 64 g x 8 kb
  wfrag_kernel<<<dim3(128), blk, 0, stream>>>(fc2w, f2F, 256, 1024);   // 16 g x 32 kb
  concat_bias_kernel<<<dim3(3), blk, 0, stream>>>(bq, bk, bv, bqkv);

  ln1_kernel<<<NPIX / 32, blk, 0, stream>>>(x, ln1g, ln1b, n1);

  // fused QKV: [N,256] x frag(768,256) -> qkv [N,768]
  gemm_blds<12, 768, 0><<<dim3(NPIX / 128), blk, 0, stream>>>(n1, wqkvF, bqkv, qkv);

  attn_kernel<<<NPIX / 4, blk, 0, stream>>>(qkv, attnb);

  res_ln2_kernel<<<NPIX / 32, blk, 0, stream>>>(x, attnb, ln2g, ln2b, x1, n2);

  // fc1 + gelu: [N,256] x frag(1024,256) -> h [N,1024]
  gemm_blds<16, 1024, 1><<<dim3(NPIX / 128), blk, 0, stream>>>(n2, f1F, fc1b, hbuf);

  // fc2 + residual + transpose: [N,1024] x frag(256,1024) -> out [B,C,H,W]
  fc2_kernel<<<dim3((NPIX / 128) * 2), blk, 0, stream>>>(hbuf, f2F, fc2b, x1, out);
}